// Round 7
// baseline (1260.049 us; speedup 1.0000x reference)
//
#include <hip/hip_runtime.h>
#include <hip/hip_bf16.h>
#include <hip/hip_cooperative_groups.h>

namespace cg = cooperative_groups;

// ---------------- types ----------------
typedef __bf16 bf16x8 __attribute__((__ext_vector_type__(8)));
typedef __bf16 bf16x4 __attribute__((__ext_vector_type__(4)));
typedef float  f32x4  __attribute__((__ext_vector_type__(4)));

#define MFMA16(a, b, c) __builtin_amdgcn_mfma_f32_16x16x32_bf16((a), (b), (c), 0, 0, 0)

static constexpr int   NSEQ  = 2304;   // 48*48
static constexpr float SCALE = 0.17677669529663687f;  // 32^-0.5
static constexpr float LOG2E = 1.44269504088896340736f;
static constexpr int   KVS   = 6;      // kv split factor
static constexpr float DEFER_THR = 11.5f;  // log2-domain defer-max threshold

// XOR swizzle for [rows][256] bf16 LDS tiles (row stride 512B).
#define SWZ(row, colByte) ((row) * 512 + ((colByte) ^ (((row) & 7) << 4)))

struct KP {
    const float *x, *g1, *b1, *wqkv, *wproj, *bproj, *btab, *g2, *b2, *wfc1, *bfc1, *wfc2, *bfc2;
    __hip_bfloat16 *wqkvT, *wprojT, *wfc1T, *wfc2T;
    float *btabT;
    __hip_bfloat16 *Qb, *Kb, *Vt;
    float *x2, *Pm, *Pl;
    __hip_bfloat16 *PO, *hb;
    float *out;
};

// ================= phase 0: weight transpose + bias table =================
__device__ __forceinline__ void prep_phase(const KP& p, int b, char* smemc)
{
    int tid = threadIdx.x;
    if (b >= 768) {   // bias table [9025][8] -> [8][9025], log2 domain
        int base = (b - 768) * 1024;
        for (int k = tid; k < 1024; k += 256) {
            int e = base + k;
            if (e < 72200) { int i = e >> 3, hh = e & 7; p.btabT[hh * 9025 + i] = p.btab[e] * LOG2E; }
        }
        return;
    }
    const float* src; __hip_bfloat16* dst; int K, N, t;
    if (b < 192)      { src = p.wqkv;  dst = p.wqkvT;  K = 256;  N = 768;  t = b;       }
    else if (b < 256) { src = p.wproj; dst = p.wprojT; K = 256;  N = 256;  t = b - 192; }
    else if (b < 512) { src = p.wfc1;  dst = p.wfc1T;  K = 256;  N = 1024; t = b - 256; }
    else              { src = p.wfc2;  dst = p.wfc2T;  K = 1024; N = 256;  t = b - 512; }
    int ntn = N >> 5;
    int tk = t / ntn, tn = t % ntn;
    float (*tile)[33] = (float (*)[33])smemc;
    int tx = tid & 31, ty = tid >> 5;   // 32 x 8
    #pragma unroll
    for (int r = 0; r < 4; ++r)
        tile[ty + 8 * r][tx] = src[(size_t)(tk * 32 + ty + 8 * r) * N + tn * 32 + tx];
    __syncthreads();
    #pragma unroll
    for (int r = 0; r < 4; ++r)
        dst[(size_t)(tn * 32 + ty + 8 * r) * K + tk * 32 + tx] =
            __float2bfloat16(tile[tx][ty + 8 * r]);
}

// ================= phase 1: LN1 + QKV GEMM (32 rows x 64 cols, 864 units) =================
__device__ __forceinline__ void qkv_phase(const KP& p, int u, char* smem)
{
    int tid = threadIdx.x;
    int un = u % 12, um = u / 12;
    int bn = un * 64, bm = um * 32;

    {   // LN prologue: 8 lanes per row
        int row = tid >> 3, part = tid & 7;
        const float* xr = p.x + (size_t)(bm + row) * 256 + part * 32;
        float vals[32];
        float s = 0.f, s2 = 0.f;
        #pragma unroll
        for (int i = 0; i < 8; ++i) {
            f32x4 v4 = *reinterpret_cast<const f32x4*>(xr + 4 * i);
            #pragma unroll
            for (int e = 0; e < 4; ++e) {
                vals[4 * i + e] = v4[e];
                s += v4[e]; s2 += v4[e] * v4[e];
            }
        }
        s  += __shfl_xor(s, 1);  s  += __shfl_xor(s, 2);  s  += __shfl_xor(s, 4);
        s2 += __shfl_xor(s2, 1); s2 += __shfl_xor(s2, 2); s2 += __shfl_xor(s2, 4);
        float mu   = s * (1.f / 256.f);
        float var  = s2 * (1.f / 256.f) - mu * mu;
        float rstd = rsqrtf(var + 1e-5f);
        #pragma unroll
        for (int i = 0; i < 8; ++i) {
            int c = part * 32 + 4 * i;
            f32x4 gv = *reinterpret_cast<const f32x4*>(p.g1 + c);
            f32x4 bv = *reinterpret_cast<const f32x4*>(p.b1 + c);
            bf16x4 pk;
            #pragma unroll
            for (int e = 0; e < 4; ++e)
                pk[e] = (__bf16)((vals[4 * i + e] - mu) * rstd * gv[e] + bv[e]);
            *reinterpret_cast<bf16x4*>(smem + SWZ(row, c * 2)) = pk;
        }
    }
    __syncthreads();

    int w = tid >> 6, lane = tid & 63, l15 = lane & 15, g = lane >> 4;
    int wr = w >> 1, wc = w & 1;
    f32x4 acc[2];
    acc[0] = (f32x4){0.f, 0.f, 0.f, 0.f};
    acc[1] = (f32x4){0.f, 0.f, 0.f, 0.f};
    const __hip_bfloat16* Brow = p.wqkvT + (size_t)(bn + wc * 32 + l15) * 256 + 8 * g;
    bf16x8 p0[2][2], p1[2][2];   // [ks][fj]

#define QLOADB(dst, kb) { \
    _Pragma("unroll") for (int ks = 0; ks < 2; ++ks) \
    _Pragma("unroll") for (int fj = 0; fj < 2; ++fj) \
        dst[ks][fj] = *reinterpret_cast<const bf16x8*>(Brow + (size_t)16 * fj * 256 + (kb) + 32 * ks); }
#define QCOMP(src, kb) { \
    _Pragma("unroll") for (int ks = 0; ks < 2; ++ks) { \
        bf16x8 af = *reinterpret_cast<const bf16x8*>(smem + SWZ(wr * 16 + l15, 2 * ((kb) + 32 * ks + 8 * g))); \
        _Pragma("unroll") for (int fj = 0; fj < 2; ++fj) \
            acc[fj] = MFMA16(af, src[ks][fj], acc[fj]); } }

    QLOADB(p0, 0);
    QLOADB(p1, 64);
    QCOMP(p0, 0);
    QLOADB(p0, 128);
    QCOMP(p1, 64);
    QLOADB(p1, 192);
    QCOMP(p0, 128);
    QCOMP(p1, 192);
#undef QLOADB
#undef QCOMP

    if (bn >= 512) {   // V: LDS transpose for coalesced [h][d][n] stores
        __syncthreads();
        float* vtile = (float*)smem;   // [32][65]
        #pragma unroll
        for (int fj = 0; fj < 2; ++fj)
        #pragma unroll
        for (int j = 0; j < 4; ++j)
            vtile[(wr * 16 + 4 * g + j) * 65 + wc * 32 + 16 * fj + l15] = acc[fj][j];
        __syncthreads();
        for (int e = tid; e < 2048; e += 256) {
            int mi = e & 31, ni = e >> 5;
            int n = bn + ni;
            int h = (n >> 5) & 7, d = n & 31;
            p.Vt[(size_t)(h * 32 + d) * NSEQ + bm + mi] = __float2bfloat16(vtile[mi * 65 + ni]);
        }
        return;
    }
    #pragma unroll
    for (int fj = 0; fj < 2; ++fj)
    #pragma unroll
    for (int j = 0; j < 4; ++j) {
        int m = bm + wr * 16 + 4 * g + j;
        int n = bn + wc * 32 + 16 * fj + l15;
        float v = acc[fj][j];
        int which = n >> 8, h = (n >> 5) & 7, d = n & 31;
        if (which == 0) p.Qb[((size_t)(h * NSEQ + m) << 5) + d] = __float2bfloat16(v * (SCALE * LOG2E));
        else            p.Kb[((size_t)(h * NSEQ + m) << 5) + d] = __float2bfloat16(v);
    }
}

// ================= phase 2: flash attention (1728 units) =================
__device__ __forceinline__ void attn_phase(const KP& p, int u, char* smem)
{
    float* bias_l = (float*)smem;                              // 10*96*4 = 3840B
    __hip_bfloat16 (*P_lds)[16][72] =
        (__hip_bfloat16 (*)[16][72])(smem + 4096);             // 9216B

    int h = u / (36 * KVS);
    int r = u - h * (36 * KVS);
    int qt = r / KVS, kvq = r - qt * KVS;
    int tid = threadIdx.x;
    int w = tid >> 6, lane = tid & 63, l15 = lane & 15, g = lane >> 4;

    int q0 = qt * 64;
    int i1min = q0 / 48, i1max = (q0 + 63) / 48;
    int dimin = i1min - (kvq * 8 + 7);
    int nrow = (i1max - i1min) + 8;      // <= 10

    __syncthreads();   // guard smem reuse (prev phase / prev u)
    for (int i = tid; i < nrow * 95; i += 256) {
        int rr = i / 95, cc = i - rr * 95;
        bias_l[rr * 96 + 94 - cc] = p.btabT[h * 9025 + (dimin + rr + 47) * 95 + cc];
    }
    __syncthreads();

    int qrow = q0 + w * 16 + l15;
    int i1 = qrow / 48, j1 = qrow - i1 * 48;
    int colBase = (i1 - dimin) * 96 + 47 - j1;   // addr = colBase - 96*i2 + j2
    bf16x8 qf = *reinterpret_cast<const bf16x8*>(p.Qb + ((size_t)(h * NSEQ + qrow) << 5) + 8 * g);

    float m_st = -1e30f, l_st = 0.f;   // l_st: lane-partial sum
    f32x4 o0 = (f32x4){0.f, 0.f, 0.f, 0.f};
    f32x4 o1 = (f32x4){0.f, 0.f, 0.f, 0.f};
    const f32x4 zero = (f32x4){0.f, 0.f, 0.f, 0.f};
    int kvbase = kvq * 384;

    const __hip_bfloat16* Kbase = p.Kb + ((size_t)(h * NSEQ + l15) << 5) + 8 * g;

    bf16x8 kf[4], kn[4];
    #pragma unroll
    for (int s = 0; s < 4; ++s)
        kn[s] = *reinterpret_cast<const bf16x8*>(Kbase + ((size_t)(kvbase + 16 * s) << 5));

    for (int t = 0; t < 6; ++t) {
        int kv0 = kvbase + t * 64;
        #pragma unroll
        for (int s = 0; s < 4; ++s) kf[s] = kn[s];
        bf16x8 vf[4];
        #pragma unroll
        for (int uu = 0; uu < 4; ++uu) {
            int dt = uu >> 1, hh = uu & 1;
            vf[uu] = *reinterpret_cast<const bf16x8*>(
                p.Vt + (size_t)((h << 5) + 16 * dt + l15) * NSEQ + kv0 + 32 * hh + 8 * g);
        }
        if (t < 5) {
            #pragma unroll
            for (int s = 0; s < 4; ++s)
                kn[s] = *reinterpret_cast<const bf16x8*>(
                    Kbase + ((size_t)(kv0 + 64 + 16 * s) << 5));
        }
        f32x4 st[4];
        #pragma unroll
        for (int s = 0; s < 4; ++s)
            st[s] = MFMA16(kf[s], qf, zero);   // S^T[kv][q], log2 domain

        float pp[4][4];
        float ms[4];
        #pragma unroll
        for (int s = 0; s < 4; ++s) {
            int kvb = kv0 + 16 * s + 4 * g;
            int i2 = kvb / 48;
            int j2b = kvb - 48 * i2;
            int a0 = colBase - 96 * i2 + j2b;
            #pragma unroll
            for (int j = 0; j < 4; ++j) {
                int addr = a0 + j - ((j2b + j >= 48) ? 144 : 0);
                pp[s][j] = st[s][j] + bias_l[addr];
            }
            ms[s] = fmaxf(fmaxf(pp[s][0], pp[s][1]), fmaxf(pp[s][2], pp[s][3]));
        }
        float mx = fmaxf(fmaxf(ms[0], ms[1]), fmaxf(ms[2], ms[3]));
        float mn = m_st;
        if (!__all(mx <= m_st + DEFER_THR)) {
            float mxf = fmaxf(mx, __shfl_xor(mx, 16));
            mxf = fmaxf(mxf, __shfl_xor(mxf, 32));
            mn = fmaxf(m_st, mxf);
            float sc = exp2f(m_st - mn);
            m_st = mn;
            l_st *= sc;
            float scr[4];
            #pragma unroll
            for (int j = 0; j < 4; ++j) scr[j] = __shfl(sc, 4 * g + j);
            #pragma unroll
            for (int j = 0; j < 4; ++j) { o0[j] *= scr[j]; o1[j] *= scr[j]; }
        }
        float rsum[4];
        #pragma unroll
        for (int s = 0; s < 4; ++s) {
            #pragma unroll
            for (int j = 0; j < 4; ++j) pp[s][j] = exp2f(pp[s][j] - mn);
            rsum[s] = (pp[s][0] + pp[s][1]) + (pp[s][2] + pp[s][3]);
        }
        l_st += (rsum[0] + rsum[1]) + (rsum[2] + rsum[3]);
        #pragma unroll
        for (int s = 0; s < 4; ++s) {
            bf16x4 pk = { (__bf16)pp[s][0], (__bf16)pp[s][1], (__bf16)pp[s][2], (__bf16)pp[s][3] };
            *reinterpret_cast<bf16x4*>(&P_lds[w][l15][16 * s + 4 * g]) = pk;
        }
        #pragma unroll
        for (int hh = 0; hh < 2; ++hh) {
            bf16x8 pf = *reinterpret_cast<const bf16x8*>(&P_lds[w][l15][32 * hh + 8 * g]);
            o0 = MFMA16(pf, vf[hh], o0);
            o1 = MFMA16(pf, vf[2 + hh], o1);
        }
    }

    float l_red = l_st + __shfl_xor(l_st, 16);
    l_red += __shfl_xor(l_red, 32);

    size_t mb = (size_t)(kvq * 8 + h) * NSEQ;
    if (g == 0) { p.Pm[mb + qrow] = m_st; p.Pl[mb + qrow] = l_red; }
    #pragma unroll
    for (int dt = 0; dt < 2; ++dt)
        #pragma unroll
        for (int j = 0; j < 4; ++j) {
            int row = q0 + w * 16 + 4 * g + j;
            p.PO[(mb + row) * 32 + 16 * dt + l15] =
                __float2bfloat16(dt == 0 ? o0[j] : o1[j]);
        }
}

// ================= phase 3: merge + proj + residual (576 units) =================
__device__ __forceinline__ void proj_phase(const KP& p, int u, char* smem)
{
    int tid = threadIdx.x;
    int q0 = (u >> 2) * 16, bn = (u & 3) * 64;

    {   // merge prologue
        int row = tid >> 4;            // 0..15
        int c0  = (tid & 15) * 16;
        int h = c0 >> 5, d = c0 & 31;
        float m[KVS], l[KVS], a[KVS];
        #pragma unroll
        for (int k = 0; k < KVS; ++k) {
            size_t mb = (size_t)(k * 8 + h) * NSEQ + q0 + row;
            m[k] = p.Pm[mb]; l[k] = p.Pl[mb];
        }
        float M = m[0];
        #pragma unroll
        for (int k = 1; k < KVS; ++k) M = fmaxf(M, m[k]);
        float L = 0.f;
        #pragma unroll
        for (int k = 0; k < KVS; ++k) { a[k] = exp2f(m[k] - M); L += a[k] * l[k]; }
        float inv = 1.f / L;
        float o[16];
        #pragma unroll
        for (int e = 0; e < 16; ++e) o[e] = 0.f;
        #pragma unroll
        for (int k = 0; k < KVS; ++k) {
            const __hip_bfloat16* pr = p.PO + ((size_t)(k * 8 + h) * NSEQ + q0 + row) * 32 + d;
            bf16x8 po0 = *reinterpret_cast<const bf16x8*>(pr);
            bf16x8 po1 = *reinterpret_cast<const bf16x8*>(pr + 8);
            #pragma unroll
            for (int e = 0; e < 8; ++e) {
                o[e]     += a[k] * (float)po0[e];
                o[8 + e] += a[k] * (float)po1[e];
            }
        }
        #pragma unroll
        for (int i = 0; i < 4; ++i) {
            bf16x4 pk;
            #pragma unroll
            for (int e = 0; e < 4; ++e) pk[e] = (__bf16)(o[4 * i + e] * inv);
            *reinterpret_cast<bf16x4*>(smem + SWZ(row, (c0 + 4 * i) * 2)) = pk;
        }
    }
    __syncthreads();

    int w = tid >> 6, lane = tid & 63, l15 = lane & 15, g = lane >> 4;
    f32x4 acc = (f32x4){0.f, 0.f, 0.f, 0.f};
    const __hip_bfloat16* Brow = p.wprojT + (size_t)(bn + w * 16 + l15) * 256 + 8 * g;
    bf16x8 p0[2], p1[2];

#define PLOADB(dst, kb) { \
    _Pragma("unroll") for (int ks = 0; ks < 2; ++ks) \
        dst[ks] = *reinterpret_cast<const bf16x8*>(Brow + (kb) + 32 * ks); }
#define PCOMP(src, kb) { \
    _Pragma("unroll") for (int ks = 0; ks < 2; ++ks) { \
        bf16x8 af = *reinterpret_cast<const bf16x8*>(smem + SWZ(l15, 2 * ((kb) + 32 * ks + 8 * g))); \
        acc = MFMA16(af, src[ks], acc); } }

    PLOADB(p0, 0);
    PLOADB(p1, 64);
    PCOMP(p0, 0);
    PLOADB(p0, 128);
    PCOMP(p1, 64);
    PLOADB(p1, 192);
    PCOMP(p0, 128);
    PCOMP(p1, 192);
#undef PLOADB
#undef PCOMP

    #pragma unroll
    for (int j = 0; j < 4; ++j) {
        int m = q0 + 4 * g + j;
        int n = bn + w * 16 + l15;
        p.x2[(size_t)m * 256 + n] = acc[j] + p.bproj[n] + p.x[(size_t)m * 256 + n];
    }
}

// ================= phase 4: LN2 + fc1 + gelu (576 units, 32r x 128c) =================
__device__ __forceinline__ void fc1_phase(const KP& p, int u, char* smem)
{
    int tid = threadIdx.x;
    int un = u & 7, um = u >> 3;
    int bn = un * 128, bm = um * 32;

    {   // LN2 prologue: 8 lanes per row
        int row = tid >> 3, part = tid & 7;
        const float* xr = p.x2 + (size_t)(bm + row) * 256 + part * 32;
        float vals[32];
        float s = 0.f, s2 = 0.f;
        #pragma unroll
        for (int i = 0; i < 8; ++i) {
            f32x4 v4 = *reinterpret_cast<const f32x4*>(xr + 4 * i);
            #pragma unroll
            for (int e = 0; e < 4; ++e) {
                vals[4 * i + e] = v4[e];
                s += v4[e]; s2 += v4[e] * v4[e];
            }
        }
        s  += __shfl_xor(s, 1);  s  += __shfl_xor(s, 2);  s  += __shfl_xor(s, 4);
        s2 += __shfl_xor(s2, 1); s2 += __shfl_xor(s2, 2); s2 += __shfl_xor(s2, 4);
        float mu   = s * (1.f / 256.f);
        float var  = s2 * (1.f / 256.f) - mu * mu;
        float rstd = rsqrtf(var + 1e-5f);
        #pragma unroll
        for (int i = 0; i < 8; ++i) {
            int c = part * 32 + 4 * i;
            f32x4 gv = *reinterpret_cast<const f32x4*>(p.g2 + c);
            f32x4 bv = *reinterpret_cast<const f32x4*>(p.b2 + c);
            bf16x4 pk;
            #pragma unroll
            for (int e = 0; e < 4; ++e)
                pk[e] = (__bf16)((vals[4 * i + e] - mu) * rstd * gv[e] + bv[e]);
            *reinterpret_cast<bf16x4*>(smem + SWZ(row, c * 2)) = pk;
        }
    }
    __syncthreads();

    int w = tid >> 6, lane = tid & 63, l15 = lane & 15, g = lane >> 4;
    f32x4 acc[2][2];
    #pragma unroll
    for (int i = 0; i < 2; ++i)
        #pragma unroll
        for (int j = 0; j < 2; ++j) acc[i][j] = (f32x4){0.f, 0.f, 0.f, 0.f};
    const __hip_bfloat16* Brow = p.wfc1T + (size_t)(bn + w * 32 + l15) * 256 + 8 * g;
    bf16x8 p0[2][2], p1[2][2];   // [ks][fj]

#define FLOADB(dst, kb) { \
    _Pragma("unroll") for (int ks = 0; ks < 2; ++ks) \
    _Pragma("unroll") for (int fj = 0; fj < 2; ++fj) \
        dst[ks][fj] = *reinterpret_cast<const bf16x8*>(Brow + (size_t)16 * fj * 256 + (kb) + 32 * ks); }
#define FCOMP(src, kb) { \
    _Pragma("unroll") for (int ks = 0; ks < 2; ++ks) { \
        bf16x8 af0 = *reinterpret_cast<const bf16x8*>(smem + SWZ(l15, 2 * ((kb) + 32 * ks + 8 * g))); \
        bf16x8 af1 = *reinterpret_cast<const bf16x8*>(smem + SWZ(16 + l15, 2 * ((kb) + 32 * ks + 8 * g))); \
        _Pragma("unroll") for (int fj = 0; fj < 2; ++fj) { \
            acc[0][fj] = MFMA16(af0, src[ks][fj], acc[0][fj]); \
            acc[1][fj] = MFMA16(af1, src[ks][fj], acc[1][fj]); } } }

    FLOADB(p0, 0);
    FLOADB(p1, 64);
    FCOMP(p0, 0);
    FLOADB(p0, 128);
    FCOMP(p1, 64);
    FLOADB(p1, 192);
    FCOMP(p0, 128);
    FCOMP(p1, 192);
#undef FLOADB
#undef FCOMP

    #pragma unroll
    for (int fi = 0; fi < 2; ++fi)
    #pragma unroll
    for (int fj = 0; fj < 2; ++fj)
        #pragma unroll
        for (int j = 0; j < 4; ++j) {
            int m = bm + 16 * fi + 4 * g + j;
            int n = bn + w * 32 + 16 * fj + l15;
            float rr = acc[fi][fj][j] + p.bfc1[n];
            float uu = rr * (rr * rr * 0.044715f + 1.f) * -2.302118131f;
            float gl = rr / (1.f + exp2f(uu));
            p.hb[(size_t)m * 1024 + n] = __float2bfloat16(gl);
        }
}

// ================= phase 5: fc2 + bias + residual (576 units, 64r x 16c) =================
__device__ __forceinline__ void fc2_phase(const KP& p, int u)
{
    int tid = threadIdx.x;
    int un = u & 15, um = u >> 4;
    int bm = um * 64, bn = un * 16;
    int w = tid >> 6, lane = tid & 63, l15 = lane & 15, g = lane >> 4;

    f32x4 acc = (f32x4){0.f, 0.f, 0.f, 0.f};
    const __hip_bfloat16* Arow = p.hb + (size_t)(bm + w * 16 + l15) * 1024 + 8 * g;
    const __hip_bfloat16* Brow = p.wfc2T + (size_t)(bn + l15) * 1024 + 8 * g;

    bf16x8 ab[3][2], bb[3][2];
#define LOADC(ib, kb) { \
    _Pragma("unroll") for (int ks = 0; ks < 2; ++ks) { \
        ab[ib][ks] = *reinterpret_cast<const bf16x8*>(Arow + (kb) + 32 * ks); \
        bb[ib][ks] = *reinterpret_cast<const bf16x8*>(Brow + (kb) + 32 * ks); } }
#define COMPC(ib) { \
    _Pragma("unroll") for (int ks = 0; ks < 2; ++ks) \
        acc = MFMA16(ab[ib][ks], bb[ib][ks], acc); }

    LOADC(0, 0); LOADC(1, 64); LOADC(2, 128);
    #pragma unroll
    for (int t = 0; t < 16; ++t) {
        COMPC(t % 3);
        if (t + 3 < 16) LOADC(t % 3, 64 * (t + 3));
    }
#undef LOADC
#undef COMPC

    #pragma unroll
    for (int j = 0; j < 4; ++j) {
        int m = bm + w * 16 + 4 * g + j;
        int n = bn + l15;
        p.out[(size_t)m * 256 + n] = acc[j] + p.bfc2[n] + p.x2[(size_t)m * 256 + n];
    }
}

// ================= mega cooperative kernel =================
__global__ __launch_bounds__(256, 4) void mega_kernel(KP p)
{
    __shared__ __align__(16) char smem[16384];
    cg::grid_group grid = cg::this_grid();
    int bid = blockIdx.x;

    if (bid < 839) prep_phase(p, bid, smem);
    __threadfence();
    grid.sync();

    if (bid < 864) qkv_phase(p, bid, smem);
    __threadfence();
    grid.sync();

    for (int u = bid; u < 8 * 36 * KVS; u += 1024) attn_phase(p, u, smem);
    __threadfence();
    grid.sync();

    if (bid < 576) proj_phase(p, bid, smem);
    __threadfence();
    grid.sync();

    if (bid < 576) fc1_phase(p, bid, smem);
    __threadfence();
    grid.sync();

    if (bid < 576) fc2_phase(p, bid);
}

// ================= fallback wrappers (separate launches, R6 behavior) =================
__global__ __launch_bounds__(256) void k_prep(KP p)
{ __shared__ __align__(16) char smem[16384]; prep_phase(p, blockIdx.x, smem); }
__global__ __launch_bounds__(256) void k_qkv(KP p)
{ __shared__ __align__(16) char smem[16384]; qkv_phase(p, blockIdx.x, smem); }
__global__ __launch_bounds__(256) void k_attn(KP p)
{ __shared__ __align__(16) char smem[16384]; attn_phase(p, blockIdx.x, smem); }
__global__ __launch_bounds__(256) void k_proj(KP p)
{ __shared__ __align__(16) char smem[16384]; proj_phase(p, blockIdx.x, smem); }
__global__ __launch_bounds__(256) void k_fc1(KP p)
{ __shared__ __align__(16) char smem[16384]; fc1_phase(p, blockIdx.x, smem); }
__global__ __launch_bounds__(256) void k_fc2(KP p)
{ fc2_phase(p, blockIdx.x); }

// ---------------- launch ----------------
extern "C" void kernel_launch(void* const* d_in, const int* in_sizes, int n_in,
                              void* d_out, int out_size, void* d_ws, size_t ws_size,
                              hipStream_t stream)
{
    char* ws = (char*)d_ws;
    size_t off = 0;
    auto alloc = [&](size_t bytes) -> void* {
        void* pp = ws + off;
        off += (bytes + 255) & ~(size_t)255;
        return pp;
    };

    KP p;
    p.x      = (const float*)d_in[0];
    p.g1     = (const float*)d_in[1];
    p.b1     = (const float*)d_in[2];
    p.wqkv   = (const float*)d_in[3];
    p.wproj  = (const float*)d_in[4];
    p.bproj  = (const float*)d_in[5];
    p.btab   = (const float*)d_in[6];
    p.g2     = (const float*)d_in[7];
    p.b2     = (const float*)d_in[8];
    p.wfc1   = (const float*)d_in[9];
    p.bfc1   = (const float*)d_in[10];
    p.wfc2   = (const float*)d_in[11];
    p.bfc2   = (const float*)d_in[12];
    // d_in[13] rel_idx: recomputed analytically in-kernel.

    p.wqkvT = (__hip_bfloat16*)alloc((size_t)768 * 256 * 2);
    p.wprojT= (__hip_bfloat16*)alloc((size_t)256 * 256 * 2);
    p.wfc1T = (__hip_bfloat16*)alloc((size_t)1024 * 256 * 2);
    p.wfc2T = (__hip_bfloat16*)alloc((size_t)256 * 1024 * 2);
    p.btabT = (float*)alloc((size_t)8 * 9025 * 4);
    p.Qb    = (__hip_bfloat16*)alloc((size_t)8 * NSEQ * 32 * 2);
    p.Kb    = (__hip_bfloat16*)alloc((size_t)8 * NSEQ * 32 * 2);
    p.Vt    = (__hip_bfloat16*)alloc((size_t)8 * 32 * NSEQ * 2);
    p.x2    = (float*)alloc((size_t)NSEQ * 256 * 4);
    p.Pm    = (float*)alloc((size_t)KVS * 8 * NSEQ * 4);
    p.Pl    = (float*)alloc((size_t)KVS * 8 * NSEQ * 4);
    p.PO    = (__hip_bfloat16*)alloc((size_t)KVS * 8 * NSEQ * 32 * 2);
    p.hb    = (__hip_bfloat16*)alloc((size_t)NSEQ * 1024 * 2);
    p.out   = (float*)d_out;

    void* args[] = { (void*)&p };
    hipError_t e = hipLaunchCooperativeKernel((void*)mega_kernel, dim3(1024), dim3(256),
                                              args, 0, stream);
    if (e != hipSuccess) {
        // fallback: serialized phase launches (R6-equivalent)
        k_prep<<<dim3(839),  dim3(256), 0, stream>>>(p);
        k_qkv <<<dim3(864),  dim3(256), 0, stream>>>(p);
        k_attn<<<dim3(8 * 36 * KVS), dim3(256), 0, stream>>>(p);
        k_proj<<<dim3(576),  dim3(256), 0, stream>>>(p);
        k_fc1 <<<dim3(576),  dim3(256), 0, stream>>>(p);
        k_fc2 <<<dim3(576),  dim3(256), 0, stream>>>(p);
    }
}

// Round 8
// 218.041 us; speedup vs baseline: 5.7790x; 5.7790x over previous
//
#include <hip/hip_runtime.h>
#include <hip/hip_bf16.h>

// ---------------- types ----------------
typedef __bf16 bf16x8 __attribute__((__ext_vector_type__(8)));
typedef __bf16 bf16x4 __attribute__((__ext_vector_type__(4)));
typedef float  f32x4  __attribute__((__ext_vector_type__(4)));

#define MFMA16(a, b, c) __builtin_amdgcn_mfma_f32_16x16x32_bf16((a), (b), (c), 0, 0, 0)

static constexpr int   NSEQ  = 2304;   // 48*48
static constexpr float SCALE = 0.17677669529663687f;  // 32^-0.5
static constexpr float LOG2E = 1.44269504088896340736f;
static constexpr int   KVS   = 12;     // kv split factor (192 rows = 4 image rows each)
static constexpr float DEFER_THR = 11.5f;  // log2-domain defer-max threshold
static constexpr float BMARGIN   = 0.25f;  // bias upper-bound margin (log2 domain)

// XOR swizzle for [rows][256] bf16 LDS tiles (row stride 512B).
#define SWZ(row, colByte) ((row) * 512 + ((colByte) ^ (((row) & 7) << 4)))

// ---------------- weight transpose + f32->bf16 (+ bias table exp-transpose) ----------------
__global__ __launch_bounds__(256) void prep_kernel(
    const float* __restrict__ wqkv, const float* __restrict__ wproj,
    const float* __restrict__ wfc1, const float* __restrict__ wfc2,
    const float* __restrict__ btab,
    __hip_bfloat16* __restrict__ oqkv, __hip_bfloat16* __restrict__ oproj,
    __hip_bfloat16* __restrict__ ofc1, __hip_bfloat16* __restrict__ ofc2,
    float* __restrict__ btabT)
{
    int b = blockIdx.x;
    int tid = threadIdx.x;
    if (b >= 768) {   // bias table [9025][8] -> [8][9025], pre-exponentiated: e^bias
        int base = (b - 768) * 1024;
        for (int k = tid; k < 1024; k += 256) {
            int e = base + k;
            if (e < 72200) { int i = e >> 3, hh = e & 7; btabT[hh * 9025 + i] = expf(btab[e]); }
        }
        return;
    }
    const float* src; __hip_bfloat16* dst; int K, N, t;
    if (b < 192)      { src = wqkv;  dst = oqkv;  K = 256;  N = 768;  t = b;       }
    else if (b < 256) { src = wproj; dst = oproj; K = 256;  N = 256;  t = b - 192; }
    else if (b < 512) { src = wfc1;  dst = ofc1;  K = 256;  N = 1024; t = b - 256; }
    else              { src = wfc2;  dst = ofc2;  K = 1024; N = 256;  t = b - 512; }
    int ntn = N >> 5;
    int tk = t / ntn, tn = t % ntn;
    __shared__ float tile[32][33];
    int tx = tid & 31, ty = tid >> 5;   // 32 x 8
    #pragma unroll
    for (int r = 0; r < 4; ++r)
        tile[ty + 8 * r][tx] = src[(size_t)(tk * 32 + ty + 8 * r) * N + tn * 32 + tx];
    __syncthreads();
    #pragma unroll
    for (int r = 0; r < 4; ++r)
        dst[(size_t)(tn * 32 + ty + 8 * r) * K + tk * 32 + tx] =
            __float2bfloat16(tile[tx][ty + 8 * r]);
}

// ---------------- fused LN1 + QKV GEMM ----------------
// grid (12, 144): 16 rows x 64 cols of [Q|K|V]. 4 waves (16 cols each), depth-2 B pipeline.
__global__ __launch_bounds__(256) void qkv_ln_kernel(
    const float* __restrict__ x, const float* __restrict__ g1,
    const float* __restrict__ b1, const __hip_bfloat16* __restrict__ BT,
    __hip_bfloat16* __restrict__ Qb, __hip_bfloat16* __restrict__ Kb,
    __hip_bfloat16* __restrict__ Vt)
{
    __shared__ char smem[16 * 512];    // A-tile [16][256] bf16 swizzled; V blocks reuse
    int tid = threadIdx.x;
    int bn = blockIdx.x * 64, bm = blockIdx.y * 16;

    // --- LN prologue: 16 lanes per row ---
    {
        int row = tid >> 4, part = tid & 15;
        const float* xr = x + (size_t)(bm + row) * 256 + part * 16;
        float vals[16];
        float s = 0.f, s2 = 0.f;
        #pragma unroll
        for (int i = 0; i < 4; ++i) {
            f32x4 v4 = *reinterpret_cast<const f32x4*>(xr + 4 * i);
            #pragma unroll
            for (int e = 0; e < 4; ++e) {
                vals[4 * i + e] = v4[e];
                s += v4[e]; s2 += v4[e] * v4[e];
            }
        }
        s  += __shfl_xor(s, 1);  s  += __shfl_xor(s, 2);
        s  += __shfl_xor(s, 4);  s  += __shfl_xor(s, 8);
        s2 += __shfl_xor(s2, 1); s2 += __shfl_xor(s2, 2);
        s2 += __shfl_xor(s2, 4); s2 += __shfl_xor(s2, 8);
        float mu   = s * (1.f / 256.f);
        float var  = s2 * (1.f / 256.f) - mu * mu;
        float rstd = rsqrtf(var + 1e-5f);
        #pragma unroll
        for (int i = 0; i < 4; ++i) {
            int c = part * 16 + 4 * i;
            f32x4 gv = *reinterpret_cast<const f32x4*>(g1 + c);
            f32x4 bv = *reinterpret_cast<const f32x4*>(b1 + c);
            bf16x4 pk;
            #pragma unroll
            for (int e = 0; e < 4; ++e)
                pk[e] = (__bf16)((vals[4 * i + e] - mu) * rstd * gv[e] + bv[e]);
            *reinterpret_cast<bf16x4*>(smem + SWZ(row, c * 2)) = pk;
        }
    }
    __syncthreads();

    // --- GEMM: wave w covers cols bn + w*16 ---
    int w = tid >> 6, lane = tid & 63, l15 = lane & 15, g = lane >> 4;
    f32x4 acc = (f32x4){0.f, 0.f, 0.f, 0.f};
    const __hip_bfloat16* Brow = BT + (size_t)(bn + w * 16 + l15) * 256 + 8 * g;
    bf16x8 p0[2], p1[2];

#define QLOADB(dst, kb) { \
    _Pragma("unroll") for (int ks = 0; ks < 2; ++ks) \
        dst[ks] = *reinterpret_cast<const bf16x8*>(Brow + (kb) + 32 * ks); }
#define QCOMP(src, kb) { \
    _Pragma("unroll") for (int ks = 0; ks < 2; ++ks) { \
        bf16x8 af = *reinterpret_cast<const bf16x8*>(smem + SWZ(l15, 2 * ((kb) + 32 * ks + 8 * g))); \
        acc = MFMA16(af, src[ks], acc); } }

    QLOADB(p0, 0);
    QLOADB(p1, 64);
    QCOMP(p0, 0);
    QLOADB(p0, 128);
    QCOMP(p1, 64);
    QLOADB(p1, 192);
    QCOMP(p0, 128);
    QCOMP(p1, 192);
#undef QLOADB
#undef QCOMP

    // --- epilogue ---
    if (bn >= 512) {   // V: LDS transpose for coalesced [h][d][n] stores
        __syncthreads();
        float* vtile = (float*)smem;   // [16][65]
        #pragma unroll
        for (int j = 0; j < 4; ++j)
            vtile[(4 * g + j) * 65 + w * 16 + l15] = acc[j];
        __syncthreads();
        for (int e = tid; e < 1024; e += 256) {
            int mi = e & 15, ni = e >> 4;
            int n = bn + ni;
            int h = (n >> 5) & 7, d = n & 31;
            Vt[(size_t)(h * 32 + d) * NSEQ + bm + mi] = __float2bfloat16(vtile[mi * 65 + ni]);
        }
        return;
    }
    #pragma unroll
    for (int j = 0; j < 4; ++j) {
        int m = bm + 4 * g + j;
        int n = bn + w * 16 + l15;
        float v = acc[j];
        int which = n >> 8, h = (n >> 5) & 7, d = n & 31;
        // Q pre-scaled into log2 domain for exp2-based softmax
        if (which == 0) Qb[((size_t)(h * NSEQ + m) << 5) + d] = __float2bfloat16(v * (SCALE * LOG2E));
        else            Kb[((size_t)(h * NSEQ + m) << 5) + d] = __float2bfloat16(v);
    }
}

// ---------------- flash attention, kv split 12 ways across blocks ----------------
// log2-domain softmax; multiplicative bias (e^b table); defer-max; K prefetch.
__global__ __launch_bounds__(256) void attn_kernel(
    const __hip_bfloat16* __restrict__ Q,
    const __hip_bfloat16* __restrict__ Kb,
    const __hip_bfloat16* __restrict__ Vt,     // [8][32][2304]
    const float* __restrict__ btabT,           // [8][9025], e^bias
    float* __restrict__ Pm, float* __restrict__ Pl,
    __hip_bfloat16* __restrict__ PO)           // [12][8][2304][32]
{
    __shared__ float bias_l[6 * 96];           // REVERSED cols
    __shared__ __hip_bfloat16 P_lds[4][16][72];

    int bid = blockIdx.x;
    int h = bid / (36 * KVS);
    int r = bid - h * (36 * KVS);
    int qt = r / KVS, kvq = r - qt * KVS;
    int tid = threadIdx.x;
    int w = tid >> 6, lane = tid & 63, l15 = lane & 15, g = lane >> 4;

    int q0 = qt * 64;
    int i1min = q0 / 48, i1max = (q0 + 63) / 48;
    int dimin = i1min - (kvq * 4 + 3);   // 192 kv rows = 4 image rows
    int nrow = (i1max - i1min) + 4;      // <= 6

    for (int i = tid; i < nrow * 95; i += 256) {
        int rr = i / 95, cc = i - rr * 95;
        bias_l[rr * 96 + 94 - cc] = btabT[h * 9025 + (dimin + rr + 47) * 95 + cc];
    }
    __syncthreads();

    int qrow = q0 + w * 16 + l15;
    int i1 = qrow / 48, j1 = qrow - i1 * 48;
    int colBase = (i1 - dimin) * 96 + 47 - j1;   // addr = colBase - 96*i2 + j2
    bf16x8 qf = *reinterpret_cast<const bf16x8*>(Q + ((size_t)(h * NSEQ + qrow) << 5) + 8 * g);

    float m_st = -1e30f, l_st = 0.f;   // l_st: lane-partial sum
    f32x4 o0 = (f32x4){0.f, 0.f, 0.f, 0.f};
    f32x4 o1 = (f32x4){0.f, 0.f, 0.f, 0.f};
    const f32x4 zero = (f32x4){0.f, 0.f, 0.f, 0.f};
    int kvbase = kvq * 192;

    const __hip_bfloat16* Kbase = Kb + ((size_t)(h * NSEQ + l15) << 5) + 8 * g;

    bf16x8 kf[4], kn[4];
    #pragma unroll
    for (int s = 0; s < 4; ++s)
        kn[s] = *reinterpret_cast<const bf16x8*>(Kbase + ((size_t)(kvbase + 16 * s) << 5));

    for (int t = 0; t < 3; ++t) {
        int kv0 = kvbase + t * 64;
        #pragma unroll
        for (int s = 0; s < 4; ++s) kf[s] = kn[s];
        bf16x8 vf[4];
        #pragma unroll
        for (int u = 0; u < 4; ++u) {
            int dt = u >> 1, hh = u & 1;
            vf[u] = *reinterpret_cast<const bf16x8*>(
                Vt + (size_t)((h << 5) + 16 * dt + l15) * NSEQ + kv0 + 32 * hh + 8 * g);
        }
        if (t < 2) {
            #pragma unroll
            for (int s = 0; s < 4; ++s)
                kn[s] = *reinterpret_cast<const bf16x8*>(
                    Kbase + ((size_t)(kv0 + 64 + 16 * s) << 5));
        }
        f32x4 st[4];
        #pragma unroll
        for (int s = 0; s < 4; ++s)
            st[s] = MFMA16(kf[s], qf, zero);   // S^T[kv][q], log2 domain (no bias)

        // local max tree on RAW scores (bias handled multiplicatively)
        float ms[4];
        #pragma unroll
        for (int s = 0; s < 4; ++s)
            ms[s] = fmaxf(fmaxf(st[s][0], st[s][1]), fmaxf(st[s][2], st[s][3]));
        float mx = fmaxf(fmaxf(ms[0], ms[1]), fmaxf(ms[2], ms[3]));
        float mn = m_st;
        if (!__all(mx + BMARGIN <= m_st + DEFER_THR)) {
            float mxf = fmaxf(mx, __shfl_xor(mx, 16));
            mxf = fmaxf(mxf, __shfl_xor(mxf, 32));
            mn = fmaxf(m_st, mxf + BMARGIN);
            float sc = exp2f(m_st - mn);
            m_st = mn;
            l_st *= sc;
            float scr[4];
            #pragma unroll
            for (int j = 0; j < 4; ++j) scr[j] = __shfl(sc, 4 * g + j);
            #pragma unroll
            for (int j = 0; j < 4; ++j) { o0[j] *= scr[j]; o1[j] *= scr[j]; }
        }
        // P = exp2(S - mn) * e^bias   (exp2 chain and bias gather are independent)
        float pp[4][4];
        float rsum[4];
        #pragma unroll
        for (int s = 0; s < 4; ++s) {
            int kvb = kv0 + 16 * s + 4 * g;
            int i2 = kvb / 48;
            int j2b = kvb - 48 * i2;
            int a0 = colBase - 96 * i2 + j2b;
            #pragma unroll
            for (int j = 0; j < 4; ++j) {
                int addr = a0 + j - ((j2b + j >= 48) ? 144 : 0);
                pp[s][j] = exp2f(st[s][j] - mn) * bias_l[addr];
            }
            rsum[s] = (pp[s][0] + pp[s][1]) + (pp[s][2] + pp[s][3]);
        }
        l_st += (rsum[0] + rsum[1]) + (rsum[2] + rsum[3]);
        // P -> LDS (transpose back to [q][kv]); wave-private
        #pragma unroll
        for (int s = 0; s < 4; ++s) {
            bf16x4 pk = { (__bf16)pp[s][0], (__bf16)pp[s][1], (__bf16)pp[s][2], (__bf16)pp[s][3] };
            *reinterpret_cast<bf16x4*>(&P_lds[w][l15][16 * s + 4 * g]) = pk;
        }
        // PV
        #pragma unroll
        for (int hh = 0; hh < 2; ++hh) {
            bf16x8 pf = *reinterpret_cast<const bf16x8*>(&P_lds[w][l15][32 * hh + 8 * g]);
            o0 = MFMA16(pf, vf[hh], o0);
            o1 = MFMA16(pf, vf[2 + hh], o1);
        }
    }

    float l_red = l_st + __shfl_xor(l_st, 16);
    l_red += __shfl_xor(l_red, 32);

    size_t mb = (size_t)(kvq * 8 + h) * NSEQ;
    if (g == 0) { Pm[mb + qrow] = m_st; Pl[mb + qrow] = l_red; }
    #pragma unroll
    for (int dt = 0; dt < 2; ++dt)
        #pragma unroll
        for (int j = 0; j < 4; ++j) {
            int row = q0 + w * 16 + 4 * g + j;
            PO[(mb + row) * 32 + 16 * dt + l15] =
                __float2bfloat16(dt == 0 ? o0[j] : o1[j]);
        }
}

// ---------------- fused merge + proj + residual ----------------
// grid (4, 144): 16 rows x 64 cols; 4 waves (16 cols each), depth-2 B pipeline.
__global__ __launch_bounds__(256) void proj_kernel(
    const __hip_bfloat16* __restrict__ PO, const float* __restrict__ Pm,
    const float* __restrict__ Pl, const __hip_bfloat16* __restrict__ BT,
    const float* __restrict__ bproj, const float* __restrict__ x,
    float* __restrict__ x2)
{
    __shared__ char smem[16 * 512];    // merged A-tile [16][256] bf16 swizzled
    int tid = threadIdx.x;
    int q0 = blockIdx.y * 16, bn = blockIdx.x * 64;

    {   // merge prologue: each lane 16 cols of one head
        int row = tid >> 4;            // 0..15
        int c0  = (tid & 15) * 16;
        int h = c0 >> 5, d = c0 & 31;
        float m[KVS], l[KVS], a[KVS];
        #pragma unroll
        for (int k = 0; k < KVS; ++k) {
            size_t mb = (size_t)(k * 8 + h) * NSEQ + q0 + row;
            m[k] = Pm[mb]; l[k] = Pl[mb];
        }
        float M = m[0];
        #pragma unroll
        for (int k = 1; k < KVS; ++k) M = fmaxf(M, m[k]);
        float L = 0.f;
        #pragma unroll
        for (int k = 0; k < KVS; ++k) { a[k] = exp2f(m[k] - M); L += a[k] * l[k]; }
        float inv = 1.f / L;
        float o[16];
        #pragma unroll
        for (int e = 0; e < 16; ++e) o[e] = 0.f;
        #pragma unroll
        for (int k = 0; k < KVS; ++k) {
            const __hip_bfloat16* pr = PO + ((size_t)(k * 8 + h) * NSEQ + q0 + row) * 32 + d;
            bf16x8 po0 = *reinterpret_cast<const bf16x8*>(pr);
            bf16x8 po1 = *reinterpret_cast<const bf16x8*>(pr + 8);
            #pragma unroll
            for (int e = 0; e < 8; ++e) {
                o[e]     += a[k] * (float)po0[e];
                o[8 + e] += a[k] * (float)po1[e];
            }
        }
        #pragma unroll
        for (int i = 0; i < 4; ++i) {
            bf16x4 pk;
            #pragma unroll
            for (int e = 0; e < 4; ++e) pk[e] = (__bf16)(o[4 * i + e] * inv);
            *reinterpret_cast<bf16x4*>(smem + SWZ(row, (c0 + 4 * i) * 2)) = pk;
        }
    }
    __syncthreads();

    int w = tid >> 6, lane = tid & 63, l15 = lane & 15, g = lane >> 4;
    f32x4 acc = (f32x4){0.f, 0.f, 0.f, 0.f};
    const __hip_bfloat16* Brow = BT + (size_t)(bn + w * 16 + l15) * 256 + 8 * g;
    bf16x8 p0[2], p1[2];

#define PLOADB(dst, kb) { \
    _Pragma("unroll") for (int ks = 0; ks < 2; ++ks) \
        dst[ks] = *reinterpret_cast<const bf16x8*>(Brow + (kb) + 32 * ks); }
#define PCOMP(src, kb) { \
    _Pragma("unroll") for (int ks = 0; ks < 2; ++ks) { \
        bf16x8 af = *reinterpret_cast<const bf16x8*>(smem + SWZ(l15, 2 * ((kb) + 32 * ks + 8 * g))); \
        acc = MFMA16(af, src[ks], acc); } }

    PLOADB(p0, 0);
    PLOADB(p1, 64);
    PCOMP(p0, 0);
    PLOADB(p0, 128);
    PCOMP(p1, 64);
    PLOADB(p1, 192);
    PCOMP(p0, 128);
    PCOMP(p1, 192);
#undef PLOADB
#undef PCOMP

    #pragma unroll
    for (int j = 0; j < 4; ++j) {
        int m = q0 + 4 * g + j;
        int n = bn + w * 16 + l15;
        x2[(size_t)m * 256 + n] = acc[j] + bproj[n] + x[(size_t)m * 256 + n];
    }
}

// ---------------- fused LN2 + fc1 + gelu (+ d_out prefill on bx==0) ----------------
// grid (16, 72): 32 rows x 64 cols of fc1. 4 waves (2x2), depth-2 B pipeline.
__global__ __launch_bounds__(256) void ln_fc1_kernel(
    const float* __restrict__ x2, const float* __restrict__ g2,
    const float* __restrict__ b2, const __hip_bfloat16* __restrict__ BT,
    const float* __restrict__ bfc1, const float* __restrict__ bfc2,
    __hip_bfloat16* __restrict__ hb, float* __restrict__ outPre)
{
    __shared__ char smem[32 * 512];    // A-tile [32][256] bf16 swizzled
    int tid = threadIdx.x;
    int bn = blockIdx.x * 64, bm = blockIdx.y * 32;

    // --- LN prologue: 8 lanes per row ---
    {
        int row = tid >> 3, part = tid & 7;
        const float* xr = x2 + (size_t)(bm + row) * 256 + part * 32;
        float vals[32];
        float s = 0.f, s2 = 0.f;
        #pragma unroll
        for (int i = 0; i < 8; ++i) {
            f32x4 v4 = *reinterpret_cast<const f32x4*>(xr + 4 * i);
            #pragma unroll
            for (int e = 0; e < 4; ++e) {
                vals[4 * i + e] = v4[e];
                s += v4[e]; s2 += v4[e] * v4[e];
            }
        }
        // d_out prefill = x2 + b_fc2 (one column-block worth of blocks only)
        if (blockIdx.x == 0) {
            #pragma unroll
            for (int i = 0; i < 8; ++i) {
                int c = part * 32 + 4 * i;
                f32x4 bv = *reinterpret_cast<const f32x4*>(bfc2 + c);
                f32x4 ov;
                #pragma unroll
                for (int e = 0; e < 4; ++e) ov[e] = vals[4 * i + e] + bv[e];
                *reinterpret_cast<f32x4*>(outPre + (size_t)(bm + row) * 256 + c) = ov;
            }
        }
        s  += __shfl_xor(s, 1);  s  += __shfl_xor(s, 2);  s  += __shfl_xor(s, 4);
        s2 += __shfl_xor(s2, 1); s2 += __shfl_xor(s2, 2); s2 += __shfl_xor(s2, 4);
        float mu   = s * (1.f / 256.f);
        float var  = s2 * (1.f / 256.f) - mu * mu;
        float rstd = rsqrtf(var + 1e-5f);
        #pragma unroll
        for (int i = 0; i < 8; ++i) {
            int c = part * 32 + 4 * i;
            f32x4 gv = *reinterpret_cast<const f32x4*>(g2 + c);
            f32x4 bv = *reinterpret_cast<const f32x4*>(b2 + c);
            bf16x4 pk;
            #pragma unroll
            for (int e = 0; e < 4; ++e)
                pk[e] = (__bf16)((vals[4 * i + e] - mu) * rstd * gv[e] + bv[e]);
            *reinterpret_cast<bf16x4*>(smem + SWZ(row, c * 2)) = pk;
        }
    }
    __syncthreads();

    // --- GEMM: waves 2x2, FM=1, FN=2 ---
    int w = tid >> 6, lane = tid & 63, l15 = lane & 15, g = lane >> 4;
    int wr = w >> 1, wc = w & 1;
    f32x4 acc[2];
    acc[0] = (f32x4){0.f, 0.f, 0.f, 0.f};
    acc[1] = (f32x4){0.f, 0.f, 0.f, 0.f};
    const __hip_bfloat16* Brow = BT + (size_t)(bn + wc * 32 + l15) * 256 + 8 * g;
    bf16x8 p0[2][2], p1[2][2];

#define FLOADB(dst, kb) { \
    _Pragma("unroll") for (int ks = 0; ks < 2; ++ks) \
    _Pragma("unroll") for (int fj = 0; fj < 2; ++fj) \
        dst[ks][fj] = *reinterpret_cast<const bf16x8*>(Brow + (size_t)16 * fj * 256 + (kb) + 32 * ks); }
#define FCOMP(src, kb) { \
    _Pragma("unroll") for (int ks = 0; ks < 2; ++ks) { \
        bf16x8 af = *reinterpret_cast<const bf16x8*>(smem + SWZ(wr * 16 + l15, 2 * ((kb) + 32 * ks + 8 * g))); \
        _Pragma("unroll") for (int fj = 0; fj < 2; ++fj) \
            acc[fj] = MFMA16(af, src[ks][fj], acc[fj]); } }

    FLOADB(p0, 0);
    FLOADB(p1, 64);
    FCOMP(p0, 0);
    FLOADB(p0, 128);
    FCOMP(p1, 64);
    FLOADB(p1, 192);
    FCOMP(p0, 128);
    FCOMP(p1, 192);
#undef FLOADB
#undef FCOMP

    // --- epilogue: bias + fast gelu (exp2-sigmoid) ---
    #pragma unroll
    for (int fj = 0; fj < 2; ++fj)
        #pragma unroll
        for (int j = 0; j < 4; ++j) {
            int m = bm + wr * 16 + 4 * g + j;
            int n = bn + wc * 32 + 16 * fj + l15;
            float r = acc[fj][j] + bfc1[n];
            float u = r * (r * r * 0.044715f + 1.f) * -2.302118131f;  // -2*0.79788456*log2e
            float gl = r / (1.f + exp2f(u));
            hb[(size_t)m * 1024 + n] = __float2bfloat16(gl);
        }
}

// ---------------- fc2 split-K=4: atomicAdd into prefilled d_out ----------------
// grid (16, 36, 4): 64 rows x 16 cols x K-chunk 256. 4 waves (16 rows each), depth-2.
__global__ __launch_bounds__(256) void fc2_kernel(
    const __hip_bfloat16* __restrict__ A,    // hb [2304][1024]
    const __hip_bfloat16* __restrict__ BT,   // wfc2T [256][1024]
    float* __restrict__ out)                 // prefilled x2 + b_fc2
{
    int bm = blockIdx.y * 64, bn = blockIdx.x * 16, k0 = blockIdx.z * 256;
    int tid = threadIdx.x;
    int w = tid >> 6, lane = tid & 63, l15 = lane & 15, g = lane >> 4;

    f32x4 acc = (f32x4){0.f, 0.f, 0.f, 0.f};
    const __hip_bfloat16* Arow = A  + (size_t)(bm + w * 16 + l15) * 1024 + k0 + 8 * g;
    const __hip_bfloat16* Brow = BT + (size_t)(bn + l15) * 1024 + k0 + 8 * g;

    bf16x8 a0[2], b0[2], a1[2], b1[2];
#define LOADC(ar, br, kb) { \
    _Pragma("unroll") for (int ks = 0; ks < 2; ++ks) { \
        ar[ks] = *reinterpret_cast<const bf16x8*>(Arow + (kb) + 32 * ks); \
        br[ks] = *reinterpret_cast<const bf16x8*>(Brow + (kb) + 32 * ks); } }
#define COMPC(ar, br) { \
    _Pragma("unroll") for (int ks = 0; ks < 2; ++ks) \
        acc = MFMA16(ar[ks], br[ks], acc); }

    LOADC(a0, b0, 0);
    LOADC(a1, b1, 64);
    COMPC(a0, b0);
    LOADC(a0, b0, 128);
    COMPC(a1, b1);
    LOADC(a1, b1, 192);
    COMPC(a0, b0);
    COMPC(a1, b1);
#undef LOADC
#undef COMPC

    #pragma unroll
    for (int j = 0; j < 4; ++j) {
        int m = bm + w * 16 + 4 * g + j;
        int n = bn + l15;
        atomicAdd(out + (size_t)m * 256 + n, acc[j]);
    }
}

// ---------------- launch ----------------
extern "C" void kernel_launch(void* const* d_in, const int* in_sizes, int n_in,
                              void* d_out, int out_size, void* d_ws, size_t ws_size,
                              hipStream_t stream)
{
    const float* x      = (const float*)d_in[0];
    const float* gamma1 = (const float*)d_in[1];
    const float* beta1  = (const float*)d_in[2];
    const float* w_qkv  = (const float*)d_in[3];
    const float* w_proj = (const float*)d_in[4];
    const float* b_proj = (const float*)d_in[5];
    const float* btab   = (const float*)d_in[6];
    const float* gamma2 = (const float*)d_in[7];
    const float* beta2  = (const float*)d_in[8];
    const float* w_fc1  = (const float*)d_in[9];
    const float* b_fc1  = (const float*)d_in[10];
    const float* w_fc2  = (const float*)d_in[11];
    const float* b_fc2  = (const float*)d_in[12];
    // d_in[13] rel_idx: recomputed analytically in-kernel.

    char* ws = (char*)d_ws;
    size_t off = 0;
    auto alloc = [&](size_t bytes) -> void* {
        void* p = ws + off;
        off += (bytes + 255) & ~(size_t)255;
        return p;
    };
    __hip_bfloat16* wqkvT = (__hip_bfloat16*)alloc((size_t)768 * 256 * 2);
    __hip_bfloat16* wprojT= (__hip_bfloat16*)alloc((size_t)256 * 256 * 2);
    __hip_bfloat16* wfc1T = (__hip_bfloat16*)alloc((size_t)1024 * 256 * 2);
    __hip_bfloat16* wfc2T = (__hip_bfloat16*)alloc((size_t)256 * 1024 * 2);
    float*          btabT = (float*)alloc((size_t)8 * 9025 * 4);
    __hip_bfloat16* Qb    = (__hip_bfloat16*)alloc((size_t)8 * NSEQ * 32 * 2);
    __hip_bfloat16* Kbuf  = (__hip_bfloat16*)alloc((size_t)8 * NSEQ * 32 * 2);
    __hip_bfloat16* Vt    = (__hip_bfloat16*)alloc((size_t)8 * 32 * NSEQ * 2);
    float*          x2    = (float*)alloc((size_t)NSEQ * 256 * 4);
    float*          Pm    = (float*)alloc((size_t)KVS * 8 * NSEQ * 4);
    float*          Pl    = (float*)alloc((size_t)KVS * 8 * NSEQ * 4);
    __hip_bfloat16* PO    = (__hip_bfloat16*)alloc((size_t)KVS * 8 * NSEQ * 32 * 2);
    __hip_bfloat16* hb    = (__hip_bfloat16*)alloc((size_t)NSEQ * 1024 * 2);

    prep_kernel<<<dim3(839), dim3(256), 0, stream>>>(
        w_qkv, w_proj, w_fc1, w_fc2, btab, wqkvT, wprojT, wfc1T, wfc2T, btabT);

    qkv_ln_kernel<<<dim3(12, 144), dim3(256), 0, stream>>>(
        x, gamma1, beta1, wqkvT, Qb, Kbuf, Vt);

    attn_kernel<<<dim3(8 * 36 * KVS), dim3(256), 0, stream>>>(
        Qb, Kbuf, Vt, btabT, Pm, Pl, PO);

    proj_kernel<<<dim3(4, 144), dim3(256), 0, stream>>>(
        PO, Pm, Pl, wprojT, b_proj, x, x2);

    ln_fc1_kernel<<<dim3(16, 72), dim3(256), 0, stream>>>(
        x2, gamma2, beta2, wfc1T, b_fc1, b_fc2, hb, (float*)d_out);

    fc2_kernel<<<dim3(16, 36, 4), dim3(256), 0, stream>>>(
        hb, wfc2T, (float*)d_out);
}